// Round 5
// baseline (245.547 us; speedup 1.0000x reference)
//
#include <hip/hip_runtime.h>
#include <hip/hip_cooperative_groups.h>

namespace cg = cooperative_groups;

// Problem constants (fixed by setup_inputs: N=8192, D=8, fp32).
constexpr int N = 8192;
constexpr int BLK = 256;            // threads per block
constexpr int IPT = 8;              // i-rows per thread (halves LDS-pipe share vs R3)
constexpr int ITILE = BLK * IPT;    // 2048 i-rows per unit
constexpr int NIT = N / ITILE;      // 4 i-tiles
constexpr int JTILE = 128;          // j-rows staged in LDS (4 KB)
constexpr int JCH = N / JTILE;      // 64 j-chunks
constexpr int UNITS = NIT * JCH * 2;  // 512 work units
constexpr int COOP_GRID = 512;      // 2 blocks/CU worst case — easy co-residency
constexpr int HB = 32;              // hist blocks: 4 bin-ranges x 8 value-slices

typedef float f32x2 __attribute__((ext_vector_type(2)));
typedef float f32x4 __attribute__((ext_vector_type(4)));

// Packed fp32 add: 2 diffs per instruction (j-tile stored negated; a+(-b)==a-b exactly).
__device__ __forceinline__ f32x2 pk_add(f32x2 a, f32x2 b) {
  f32x2 r;
  asm("v_pk_add_f32 %0, %1, %2" : "=v"(r) : "v"(a), "v"(b));
  return r;
}
__device__ __forceinline__ float min3f(float a, float b, float c) {
  float r;
  asm("v_min3_f32 %0, %1, %2, %3" : "=v"(r) : "v"(a), "v"(b), "v"(c));
  return r;
}
__device__ __forceinline__ float min2f(float a, float b) {
  float r;
  asm("v_min_f32 %0, %1, %2" : "=v"(r) : "v"(a), "v"(b));
  return r;
}
__device__ __forceinline__ int aload(const int* p) {
  return __hip_atomic_load(p, __ATOMIC_RELAXED, __HIP_MEMORY_SCOPE_AGENT);
}
__device__ __forceinline__ void astore(int* p, int v) {
  __hip_atomic_store(p, v, __ATOMIC_RELAXED, __HIP_MEMORY_SCOPE_AGENT);
}

// ---- Phase B unit: dominance counts for one (m, i-tile, j-chunk). ----
// counts[m*N+i] += #{ j in chunk : M[i,d] > M[j,d] for all d } via min_d(diff)>0.
// Exact: ties/self give min <= 0 (validated absmax 0.0 in R1-R3).
__device__ __forceinline__ void dom_unit(int u, const float* __restrict__ X,
                                         const float* __restrict__ Xh,
                                         int* __restrict__ counts,
                                         f32x4* tile) {
  const int tid = threadIdx.x;
  const int m = u & 1;
  const int b2 = u >> 1;
  const int it = b2 & (NIT - 1);
  const int jc = b2 >> 2;  // log2(NIT)
  const float* __restrict__ M = m ? Xh : X;
  int* cnt_out = counts + m * N;

  __syncthreads();  // protect tile reuse
  // stage NEGATED j-tile (256 f32x4 = 128 rows)
  const f32x4* src = reinterpret_cast<const f32x4*>(M + (size_t)(jc * JTILE) * 8);
  tile[tid] = -src[tid];

  const int ibase = it * ITILE + tid;
  f32x4 r0[IPT], r1[IPT];
#pragma unroll
  for (int p = 0; p < IPT; ++p) {
    const f32x4* Mi = reinterpret_cast<const f32x4*>(M + (size_t)(ibase + p * BLK) * 8);
    r0[p] = Mi[0];
    r1[p] = Mi[1];
  }
  __syncthreads();

  int cnt[IPT] = {};
#pragma unroll 2
  for (int j = 0; j < JTILE; ++j) {
    const f32x4 a = tile[2 * j];      // broadcast reads, conflict-free
    const f32x4 b = tile[2 * j + 1];
#pragma unroll
    for (int p = 0; p < IPT; ++p) {
      const f32x2 d01 = pk_add(r0[p].xy, a.xy);
      const f32x2 d23 = pk_add(r0[p].zw, a.zw);
      const f32x2 d45 = pk_add(r1[p].xy, b.xy);
      const f32x2 d67 = pk_add(r1[p].zw, b.zw);
      const float t0 = min3f(d01.x, d01.y, d23.x);
      const float t1 = min3f(d23.y, d45.x, d45.y);
      const float t2 = min3f(d67.x, d67.y, t0);
      cnt[p] += (min2f(t1, t2) > 0.0f) ? 1 : 0;
    }
  }
#pragma unroll
  for (int p = 0; p < IPT; ++p) atomicAdd(&cnt_out[ibase + p * BLK], cnt[p]);
}

// ---- Phase C: privatized difference histogram (bin-range x slice split). ----
// sum_k |sort(a)_k - sort(b)_k| == sum_t |#{a<=t} - #{b<=t}|; histogram +1 for
// X counts, -1 for Xh counts. Block hb owns bin range (hb&3)*2048.. and value
// slice (hb>>2)*2048.. -> lhist is only 8 KB; hot-bin contention /32.
__device__ __forceinline__ void hist_block(int hb, const int* __restrict__ counts,
                                           int* __restrict__ ghist, int* lhist) {
  const int tid = threadIdx.x;
  const int rg = hb & 3;
  const int sl = hb >> 2;  // 0..7
  __syncthreads();  // LDS reuse
  for (int q = tid; q < 2048; q += BLK) lhist[q] = 0;
  __syncthreads();
#pragma unroll
  for (int t = 0; t < 2048 / BLK; ++t) {
    const int k = sl * 2048 + t * BLK + tid;   // k in [0, 2N)
    const int v = aload(&counts[k]);
    if ((v >> 11) == rg) atomicAdd(&lhist[v & 2047], (k < N) ? 1 : -1);
  }
  __syncthreads();
  for (int q = tid; q < 2048; q += BLK) {
    const int h = lhist[q];
    if (h != 0) atomicAdd(&ghist[rg * 2048 + q], h);
  }
}

// ---- Phase D: one block scans the histogram and sums |prefix|. ----
__device__ __forceinline__ void fin_block(const int* __restrict__ ghist,
                                          float* __restrict__ out, int* fin) {
  const int tid = threadIdx.x;
  const int lane = tid & 63;
  const int wid = tid >> 6;
  __syncthreads();  // LDS reuse

  int local[32];  // 32 contiguous bins per thread
  int s = 0;
#pragma unroll
  for (int q = 0; q < 32; ++q) {
    local[q] = aload(&ghist[tid * 32 + q]);
    s += local[q];
  }

  int incl = s;  // wave-inclusive scan of per-thread sums
#pragma unroll
  for (int off = 1; off < 64; off <<= 1) {
    const int v = __shfl_up(incl, off);
    if (lane >= off) incl += v;
  }
  if (lane == 63) fin[wid] = incl;
  __syncthreads();
  if (tid == 0) {
    int acc = 0;
#pragma unroll
    for (int w = 0; w < 4; ++w) { const int t = fin[w]; fin[4 + w] = acc; acc += t; }
  }
  __syncthreads();

  int run = fin[4 + wid] + (incl - s);  // exclusive prefix of my chunk
  int acc = 0;
#pragma unroll
  for (int q = 0; q < 32; ++q) {
    run += local[q];
    acc += (run < 0) ? -run : run;
  }
#pragma unroll
  for (int off = 32; off > 0; off >>= 1) acc += __shfl_down(acc, off);
  if (lane == 0) fin[8 + wid] = acc;
  __syncthreads();
  if (tid == 0) {
    const int total = fin[8] + fin[9] + fin[10] + fin[11];
    out[0] = (float)((double)total / ((double)(N - 1) * (double)N));
  }
}

// ---- Fused cooperative kernel (1 dispatch instead of 4). ----
__global__ __launch_bounds__(BLK, 2) void kendall_coop(
    const float* __restrict__ X, const float* __restrict__ Xh,
    int* __restrict__ counts,   // 2N ints (ws); ghist = counts + 2N (contiguous)
    int* __restrict__ ghist,    // N ints
    float* __restrict__ out) {
  cg::grid_group g = cg::this_grid();
  __shared__ union {
    f32x4 tile[JTILE * 2];  // 4 KB
    int lhist[2048];        // 8 KB
    int fin[16];
  } smem;
  const int bid = blockIdx.x;
  const int tid = threadIdx.x;

  // Phase A: zero counts+ghist (contiguous 3N ints), device-scope stores.
  for (int k = bid * BLK + tid; k < 3 * N; k += COOP_GRID * BLK) astore(&counts[k], 0);
  g.sync();

  dom_unit(bid, X, Xh, counts, smem.tile);  // UNITS == COOP_GRID: 1 unit/block
  g.sync();

  if (bid < HB) hist_block(bid, counts, ghist, smem.lhist);
  g.sync();

  if (bid == 0) fin_block(ghist, out, smem.fin);
}

// ---- Fallback path (proven 4-node pipeline), same device functions. ----
__global__ __launch_bounds__(BLK) void dom_kernel_fb(
    const float* __restrict__ X, const float* __restrict__ Xh, int* __restrict__ counts) {
  __shared__ f32x4 tile[JTILE * 2];
  dom_unit(blockIdx.x, X, Xh, counts, tile);
}
__global__ __launch_bounds__(BLK) void hist_kernel_fb(
    const int* __restrict__ counts, int* __restrict__ ghist) {
  __shared__ int lhist[2048];
  hist_block(blockIdx.x, counts, ghist, lhist);
}
__global__ __launch_bounds__(BLK) void fin_kernel_fb(
    const int* __restrict__ ghist, float* __restrict__ out) {
  __shared__ int fin[16];
  fin_block(ghist, out, fin);
}

extern "C" void kernel_launch(void* const* d_in, const int* in_sizes, int n_in,
                              void* d_out, int out_size, void* d_ws, size_t ws_size,
                              hipStream_t stream) {
  const float* X = (const float*)d_in[0];
  const float* Xh = (const float*)d_in[1];
  float* out = (float*)d_out;
  int* counts = (int*)d_ws;      // 2N ints
  int* ghist = counts + 2 * N;   // N ints, contiguous (Phase A zeroes both)

  void* args[5] = {(void*)&X, (void*)&Xh, (void*)&counts, (void*)&ghist, (void*)&out};
  const hipError_t err = hipLaunchCooperativeKernel(
      (void*)kendall_coop, dim3(COOP_GRID), dim3(BLK), args, 0, stream);

  if (err != hipSuccess) {
    // Deterministic fallback: same phases as separate dispatches.
    hipMemsetAsync(counts, 0, 3 * N * sizeof(int), stream);
    dom_kernel_fb<<<UNITS, BLK, 0, stream>>>(X, Xh, counts);
    hist_kernel_fb<<<HB, BLK, 0, stream>>>(counts, ghist);
    fin_kernel_fb<<<1, BLK, 0, stream>>>(ghist, out);
  }
}

// Round 6
// 105.873 us; speedup vs baseline: 2.3192x; 2.3192x over previous
//
#include <hip/hip_runtime.h>

// Problem constants (fixed by setup_inputs: N=8192, D=8, fp32).
constexpr int N = 8192;
constexpr int BLK = 256;            // threads per block
constexpr int IPT = 4;              // i-rows per thread (proven reg-resident; IPT=8 demotes, R5)
constexpr int ITILE = BLK * IPT;    // 1024 i-rows per block
constexpr int JTILE = 256;          // j-rows staged in LDS per block (8 KB)
constexpr int JCH = N / JTILE;      // 32 j-chunks -> grid.y

typedef float f32x2 __attribute__((ext_vector_type(2)));
typedef float f32x4 __attribute__((ext_vector_type(4)));

// Packed fp32 add: 2 diffs per instruction (j-tile stored negated; a+(-b)==a-b exact).
__device__ __forceinline__ f32x2 pk_add(f32x2 a, f32x2 b) {
  f32x2 r;
  asm("v_pk_add_f32 %0, %1, %2" : "=v"(r) : "v"(a), "v"(b));
  return r;
}
__device__ __forceinline__ float min3f(float a, float b, float c) {
  float r;
  asm("v_min3_f32 %0, %1, %2, %3" : "=v"(r) : "v"(a), "v"(b), "v"(c));
  return r;
}
__device__ __forceinline__ float min2f(float a, float b) {
  float r;
  asm("v_min_f32 %0, %1, %2" : "=v"(r) : "v"(a), "v"(b));
  return r;
}

// counts[m*N + i] = #{ j : M[i,d] > M[j,d] for all d }
// Strict dominance via min-of-differences: min_d(Mi_d - Mj_d) > 0.
// Exact: ties/self give min <= 0 (validated absmax 0.0 in R1-R3).
__global__ __launch_bounds__(BLK) void dom_count_kernel(
    const float* __restrict__ X, const float* __restrict__ Xh,
    int* __restrict__ counts) {
  const float* M = (blockIdx.z == 0) ? X : Xh;
  int* cnt_out = counts + blockIdx.z * N;

  __shared__ f32x4 tile[JTILE * 2];   // 256 rows * 32 B = 8 KB, NEGATED

  const int tid = threadIdx.x;
  const int ibase = blockIdx.x * ITILE + tid;   // rows ibase + p*BLK

  // stage NEGATED j-tile cooperatively (coalesced f32x4 loads)
  const int j0 = blockIdx.y * JTILE;
  const f32x4* src = reinterpret_cast<const f32x4*>(M + (size_t)j0 * 8);
  for (int k = tid; k < JTILE * 2; k += BLK) tile[k] = -src[k];

  // my IPT i-rows (coalesced: consecutive lanes -> consecutive rows)
  f32x4 r0[IPT], r1[IPT];
#pragma unroll
  for (int p = 0; p < IPT; ++p) {
    const f32x4* Mi = reinterpret_cast<const f32x4*>(M + (size_t)(ibase + p * BLK) * 8);
    r0[p] = Mi[0];
    r1[p] = Mi[1];
  }
  __syncthreads();

  int cnt[IPT] = {};
#pragma unroll 2
  for (int j = 0; j < JTILE; ++j) {
    // same-address broadcast reads -> conflict-free
    const f32x4 a = tile[2 * j];
    const f32x4 b = tile[2 * j + 1];
#pragma unroll
    for (int p = 0; p < IPT; ++p) {
      const f32x2 d01 = pk_add(r0[p].xy, a.xy);   // Mi - Mj (2 dims)
      const f32x2 d23 = pk_add(r0[p].zw, a.zw);
      const f32x2 d45 = pk_add(r1[p].xy, b.xy);
      const f32x2 d67 = pk_add(r1[p].zw, b.zw);
      const float t0 = min3f(d01.x, d01.y, d23.x);
      const float t1 = min3f(d23.y, d45.x, d45.y);
      const float t2 = min3f(d67.x, d67.y, t0);
      cnt[p] += (min2f(t1, t2) > 0.0f) ? 1 : 0;
    }
  }
#pragma unroll
  for (int p = 0; p < IPT; ++p) atomicAdd(&cnt_out[ibase + p * BLK], cnt[p]);
}

// --- Finalize, stage 1: privatized histograms (R3-proven) -------------------
// sum_k |sort(a)_k - sort(b)_k| == sum_t |#{a<=t} - #{b<=t}|; histogram +1 for
// X counts, -1 for Xh counts. 16 blocks privatize hot-bin contention.
constexpr int HB = 16;
__global__ __launch_bounds__(1024) void hist_partial_kernel(
    const int* __restrict__ counts, int* __restrict__ ghist) {
  __shared__ int lhist[N];  // 32 KB
  const int tid = threadIdx.x;
  for (int q = tid; q < N; q += 1024) lhist[q] = 0;
  __syncthreads();

  const int k = blockIdx.x * (2 * N / HB) + tid;  // 1024 values per block
  const int v = counts[k];
  atomicAdd(&lhist[v], (k < N) ? 1 : -1);
  __syncthreads();

#pragma unroll
  for (int q = 0; q < N / 1024; ++q) {
    const int bin = tid * (N / 1024) + q;
    const int h = lhist[bin];
    if (h != 0) atomicAdd(&ghist[bin], h);
  }
}

// --- Finalize, stage 2: scan + abs-sum (one small block, R3-proven) ---------
__global__ __launch_bounds__(1024) void finalize_kernel(
    const int* __restrict__ ghist, float* __restrict__ out) {
  __shared__ int wsum[16];
  __shared__ int wexc[16];
  __shared__ int wabs[16];

  const int tid = threadIdx.x;
  const int lane = tid & 63;
  const int wid = tid >> 6;

  int local[8];
  int s = 0;
#pragma unroll
  for (int q = 0; q < 8; ++q) {
    local[q] = ghist[tid * 8 + q];
    s += local[q];
  }

  int incl = s;  // wave-inclusive scan of per-thread sums
#pragma unroll
  for (int off = 1; off < 64; off <<= 1) {
    const int v = __shfl_up(incl, off);
    if (lane >= off) incl += v;
  }
  if (lane == 63) wsum[wid] = incl;
  __syncthreads();

  if (tid == 0) {
    int acc = 0;
#pragma unroll
    for (int w = 0; w < 16; ++w) { wexc[w] = acc; acc += wsum[w]; }
  }
  __syncthreads();

  int run = wexc[wid] + (incl - s);  // exclusive prefix of my 8-bin chunk
  int acc = 0;
#pragma unroll
  for (int q = 0; q < 8; ++q) {
    run += local[q];
    acc += (run < 0) ? -run : run;
  }

#pragma unroll
  for (int off = 32; off > 0; off >>= 1) acc += __shfl_down(acc, off);
  if (lane == 0) wabs[wid] = acc;
  __syncthreads();

  if (tid == 0) {
    int total = 0;
#pragma unroll
    for (int w = 0; w < 16; ++w) total += wabs[w];
    // result = total / (N-1) / N
    out[0] = (float)((double)total / ((double)(N - 1) * (double)N));
  }
}

extern "C" void kernel_launch(void* const* d_in, const int* in_sizes, int n_in,
                              void* d_out, int out_size, void* d_ws, size_t ws_size,
                              hipStream_t stream) {
  const float* X = (const float*)d_in[0];
  const float* Xh = (const float*)d_in[1];
  float* out = (float*)d_out;
  int* counts = (int*)d_ws;        // 2N ints
  int* ghist = counts + 2 * N;     // N ints, contiguous

  hipMemsetAsync(counts, 0, 3 * N * sizeof(int), stream);

  dim3 grid(N / ITILE, JCH, 2);
  dom_count_kernel<<<grid, BLK, 0, stream>>>(X, Xh, counts);
  hist_partial_kernel<<<HB, 1024, 0, stream>>>(counts, ghist);
  finalize_kernel<<<1, 1024, 0, stream>>>(ghist, out);
}

// Round 7
// 103.413 us; speedup vs baseline: 2.3744x; 1.0238x over previous
//
#include <hip/hip_runtime.h>

// Problem constants (fixed by setup_inputs: N=8192, D=8, fp32).
constexpr int N = 8192;
constexpr int BLK = 256;            // threads per block
constexpr int IPT = 4;              // i-rows per thread (proven reg-resident)
constexpr int ITILE = BLK * IPT;    // 1024 i-rows per block
constexpr int JTILE = 128;          // j-rows staged in LDS (4 KB) -> 1024 blocks
constexpr int JCH = N / JTILE;      // 64 j-chunks -> grid.y
constexpr int TMASK = 2 * JTILE - 1;

typedef float f32x2 __attribute__((ext_vector_type(2)));
typedef float f32x4 __attribute__((ext_vector_type(4)));

// Packed fp32 add: 2 diffs per instruction (j-tile stored negated; a+(-b)==a-b exact).
__device__ __forceinline__ f32x2 pk_add(f32x2 a, f32x2 b) {
  f32x2 r;
  asm("v_pk_add_f32 %0, %1, %2" : "=v"(r) : "v"(a), "v"(b));
  return r;
}
__device__ __forceinline__ float min3f(float a, float b, float c) {
  float r;
  asm("v_min3_f32 %0, %1, %2, %3" : "=v"(r) : "v"(a), "v"(b), "v"(c));
  return r;
}
__device__ __forceinline__ float min2f(float a, float b) {
  float r;
  asm("v_min_f32 %0, %1, %2" : "=v"(r) : "v"(a), "v"(b));
  return r;
}

// counts[m*N + i] = #{ j : M[i,d] > M[j,d] for all d }
// Strict dominance via min-of-differences: min_d(Mi_d - Mj_d) > 0.
// Exact: ties/self give min <= 0 (validated absmax 0.0 in R1-R3/R6).
// R7: 4 blocks/CU (LDS-latency was the R6 limiter at 2 blocks/CU) + explicit
// next-j register prefetch to break the per-iter load->use chain.
__global__ __launch_bounds__(BLK) void dom_count_kernel(
    const float* __restrict__ X, const float* __restrict__ Xh,
    int* __restrict__ counts) {
  const float* M = (blockIdx.z == 0) ? X : Xh;
  int* cnt_out = counts + blockIdx.z * N;

  __shared__ f32x4 tile[JTILE * 2];   // 128 rows * 32 B = 4 KB, NEGATED

  const int tid = threadIdx.x;
  const int ibase = blockIdx.x * ITILE + tid;   // rows ibase + p*BLK

  // stage NEGATED j-tile cooperatively (coalesced f32x4 loads)
  const int j0 = blockIdx.y * JTILE;
  const f32x4* src = reinterpret_cast<const f32x4*>(M + (size_t)j0 * 8);
  for (int k = tid; k < JTILE * 2; k += BLK) tile[k] = -src[k];

  // my IPT i-rows (coalesced: consecutive lanes -> consecutive rows)
  f32x4 r0[IPT], r1[IPT];
#pragma unroll
  for (int p = 0; p < IPT; ++p) {
    const f32x4* Mi = reinterpret_cast<const f32x4*>(M + (size_t)(ibase + p * BLK) * 8);
    r0[p] = Mi[0];
    r1[p] = Mi[1];
  }
  __syncthreads();

  int cnt[IPT] = {};
  // software pipeline: a/b hold row j; an/bn prefetch row j+1 (wraparound,
  // branchless) so the broadcast ds_read latency hides under compute.
  f32x4 a = tile[0];
  f32x4 b = tile[1];
#pragma unroll 2
  for (int j = 0; j < JTILE; ++j) {
    const f32x4 an = tile[(2 * j + 2) & TMASK];
    const f32x4 bn = tile[(2 * j + 3) & TMASK];
#pragma unroll
    for (int p = 0; p < IPT; ++p) {
      const f32x2 d01 = pk_add(r0[p].xy, a.xy);   // Mi - Mj (2 dims each)
      const f32x2 d23 = pk_add(r0[p].zw, a.zw);
      const f32x2 d45 = pk_add(r1[p].xy, b.xy);
      const f32x2 d67 = pk_add(r1[p].zw, b.zw);
      const float t0 = min3f(d01.x, d01.y, d23.x);
      const float t1 = min3f(d23.y, d45.x, d45.y);
      const float t2 = min3f(d67.x, d67.y, t0);
      cnt[p] += (min2f(t1, t2) > 0.0f) ? 1 : 0;
    }
    a = an;
    b = bn;
  }
#pragma unroll
  for (int p = 0; p < IPT; ++p) atomicAdd(&cnt_out[ibase + p * BLK], cnt[p]);
}

// --- Finalize, stage 1: privatized histograms (R3-proven) -------------------
// sum_k |sort(a)_k - sort(b)_k| == sum_t |#{a<=t} - #{b<=t}|; histogram +1 for
// X counts, -1 for Xh counts. 16 blocks privatize hot-bin contention.
constexpr int HB = 16;
__global__ __launch_bounds__(1024) void hist_partial_kernel(
    const int* __restrict__ counts, int* __restrict__ ghist) {
  __shared__ int lhist[N];  // 32 KB
  const int tid = threadIdx.x;
  for (int q = tid; q < N; q += 1024) lhist[q] = 0;
  __syncthreads();

  const int k = blockIdx.x * (2 * N / HB) + tid;  // 1024 values per block
  const int v = counts[k];
  atomicAdd(&lhist[v], (k < N) ? 1 : -1);
  __syncthreads();

#pragma unroll
  for (int q = 0; q < N / 1024; ++q) {
    const int bin = tid * (N / 1024) + q;
    const int h = lhist[bin];
    if (h != 0) atomicAdd(&ghist[bin], h);
  }
}

// --- Finalize, stage 2: scan + abs-sum (one small block, R3-proven) ---------
__global__ __launch_bounds__(1024) void finalize_kernel(
    const int* __restrict__ ghist, float* __restrict__ out) {
  __shared__ int wsum[16];
  __shared__ int wexc[16];
  __shared__ int wabs[16];

  const int tid = threadIdx.x;
  const int lane = tid & 63;
  const int wid = tid >> 6;

  int local[8];
  int s = 0;
#pragma unroll
  for (int q = 0; q < 8; ++q) {
    local[q] = ghist[tid * 8 + q];
    s += local[q];
  }

  int incl = s;  // wave-inclusive scan of per-thread sums
#pragma unroll
  for (int off = 1; off < 64; off <<= 1) {
    const int v = __shfl_up(incl, off);
    if (lane >= off) incl += v;
  }
  if (lane == 63) wsum[wid] = incl;
  __syncthreads();

  if (tid == 0) {
    int acc = 0;
#pragma unroll
    for (int w = 0; w < 16; ++w) { wexc[w] = acc; acc += wsum[w]; }
  }
  __syncthreads();

  int run = wexc[wid] + (incl - s);  // exclusive prefix of my 8-bin chunk
  int acc = 0;
#pragma unroll
  for (int q = 0; q < 8; ++q) {
    run += local[q];
    acc += (run < 0) ? -run : run;
  }

#pragma unroll
  for (int off = 32; off > 0; off >>= 1) acc += __shfl_down(acc, off);
  if (lane == 0) wabs[wid] = acc;
  __syncthreads();

  if (tid == 0) {
    int total = 0;
#pragma unroll
    for (int w = 0; w < 16; ++w) total += wabs[w];
    // result = total / (N-1) / N
    out[0] = (float)((double)total / ((double)(N - 1) * (double)N));
  }
}

extern "C" void kernel_launch(void* const* d_in, const int* in_sizes, int n_in,
                              void* d_out, int out_size, void* d_ws, size_t ws_size,
                              hipStream_t stream) {
  const float* X = (const float*)d_in[0];
  const float* Xh = (const float*)d_in[1];
  float* out = (float*)d_out;
  int* counts = (int*)d_ws;        // 2N ints
  int* ghist = counts + 2 * N;     // N ints, contiguous

  hipMemsetAsync(counts, 0, 3 * N * sizeof(int), stream);

  dim3 grid(N / ITILE, JCH, 2);
  dom_count_kernel<<<grid, BLK, 0, stream>>>(X, Xh, counts);
  hist_partial_kernel<<<HB, 1024, 0, stream>>>(counts, ghist);
  finalize_kernel<<<1, 1024, 0, stream>>>(ghist, out);
}

// Round 8
// 103.096 us; speedup vs baseline: 2.3817x; 1.0031x over previous
//
#include <hip/hip_runtime.h>

// Problem constants (fixed by setup_inputs: N=8192, D=8, fp32).
constexpr int N = 8192;
constexpr int BLK = 256;            // threads per block
constexpr int IPT = 8;              // i-rows per thread: halves LDS reads/pair vs IPT=4
constexpr int ITILE = BLK * IPT;    // 2048 i-rows per block
constexpr int NIT = N / ITILE;      // 4 i-tiles
constexpr int JTILE = 64;           // j-rows staged in LDS (2 KB) -> grid 1024 = 4 blk/CU
constexpr int JCH = N / JTILE;      // 128 j-chunks -> grid.y

typedef float f32x2 __attribute__((ext_vector_type(2)));
typedef float f32x4 __attribute__((ext_vector_type(4)));

// Packed fp32 add: 2 diffs per instruction (j-tile stored negated; a+(-b)==a-b exact).
__device__ __forceinline__ f32x2 pk_add(f32x2 a, f32x2 b) {
  f32x2 r;
  asm("v_pk_add_f32 %0, %1, %2" : "=v"(r) : "v"(a), "v"(b));
  return r;
}
__device__ __forceinline__ float min3f(float a, float b, float c) {
  float r;
  asm("v_min3_f32 %0, %1, %2, %3" : "=v"(r) : "v"(a), "v"(b), "v"(c));
  return r;
}
__device__ __forceinline__ float min2f(float a, float b) {
  float r;
  asm("v_min_f32 %0, %1, %2" : "=v"(r) : "v"(a), "v"(b));
  return r;
}

// counts[m*N + i] = #{ j : M[i,d] > M[j,d] for all d }
// Strict dominance via min-of-differences: min_d(Mi_d - Mj_d) > 0.
// Exact: ties/self give min <= 0 (validated absmax 0.0 in R1-R3/R6/R7).
// R8: IPT=8 (halve LDS-pipe share per pair — the R7 throughput wall) and a
// fully unrolled-by-4 j-loop: compile-time tile indices -> ds_read_b128 with
// immediate offsets, no rotation copies, no address VALU (the R7 bloat:
// ~75 measured VALU/iter vs ~42 intended).
__global__ __launch_bounds__(BLK, 4) void dom_count_kernel(
    const float* __restrict__ X, const float* __restrict__ Xh,
    int* __restrict__ counts) {
  const float* M = (blockIdx.z == 0) ? X : Xh;
  int* cnt_out = counts + blockIdx.z * N;

  __shared__ f32x4 tile[JTILE * 2];   // 64 rows * 32 B = 2 KB, NEGATED

  const int tid = threadIdx.x;
  const int ibase = blockIdx.x * ITILE + tid;   // rows ibase + p*BLK

  // stage NEGATED j-tile (128 f32x4; only first 128 threads)
  const int j0 = blockIdx.y * JTILE;
  const f32x4* src = reinterpret_cast<const f32x4*>(M + (size_t)j0 * 8);
  if (tid < JTILE * 2) tile[tid] = -src[tid];

  // my IPT i-rows (coalesced: consecutive lanes -> consecutive rows)
  f32x4 r0[IPT], r1[IPT];
#pragma unroll
  for (int p = 0; p < IPT; ++p) {
    const f32x4* Mi = reinterpret_cast<const f32x4*>(M + (size_t)(ibase + p * BLK) * 8);
    r0[p] = Mi[0];
    r1[p] = Mi[1];
  }
  __syncthreads();

  int cnt[IPT] = {};
#pragma unroll 4
  for (int j = 0; j < JTILE; ++j) {
    // compile-time indices (unroll) -> ds_read_b128 with immediate offsets;
    // same-address broadcast reads, conflict-free
    const f32x4 a = tile[2 * j];
    const f32x4 b = tile[2 * j + 1];
#pragma unroll
    for (int p = 0; p < IPT; ++p) {
      const f32x2 d01 = pk_add(r0[p].xy, a.xy);   // Mi - Mj (2 dims each)
      const f32x2 d23 = pk_add(r0[p].zw, a.zw);
      const f32x2 d45 = pk_add(r1[p].xy, b.xy);
      const f32x2 d67 = pk_add(r1[p].zw, b.zw);
      const float t0 = min3f(d01.x, d01.y, d23.x);
      const float t1 = min3f(d23.y, d45.x, d45.y);
      const float t2 = min3f(d67.x, d67.y, t0);
      cnt[p] += (min2f(t1, t2) > 0.0f) ? 1 : 0;
    }
  }
#pragma unroll
  for (int p = 0; p < IPT; ++p) atomicAdd(&cnt_out[ibase + p * BLK], cnt[p]);
}

// --- Finalize, stage 1: privatized histograms (R3-proven) -------------------
// sum_k |sort(a)_k - sort(b)_k| == sum_t |#{a<=t} - #{b<=t}|; histogram +1 for
// X counts, -1 for Xh counts. 16 blocks privatize hot-bin contention.
constexpr int HB = 16;
__global__ __launch_bounds__(1024) void hist_partial_kernel(
    const int* __restrict__ counts, int* __restrict__ ghist) {
  __shared__ int lhist[N];  // 32 KB
  const int tid = threadIdx.x;
  for (int q = tid; q < N; q += 1024) lhist[q] = 0;
  __syncthreads();

  const int k = blockIdx.x * (2 * N / HB) + tid;  // 1024 values per block
  const int v = counts[k];
  atomicAdd(&lhist[v], (k < N) ? 1 : -1);
  __syncthreads();

#pragma unroll
  for (int q = 0; q < N / 1024; ++q) {
    const int bin = tid * (N / 1024) + q;
    const int h = lhist[bin];
    if (h != 0) atomicAdd(&ghist[bin], h);
  }
}

// --- Finalize, stage 2: scan + abs-sum (one small block, R3-proven) ---------
__global__ __launch_bounds__(1024) void finalize_kernel(
    const int* __restrict__ ghist, float* __restrict__ out) {
  __shared__ int wsum[16];
  __shared__ int wexc[16];
  __shared__ int wabs[16];

  const int tid = threadIdx.x;
  const int lane = tid & 63;
  const int wid = tid >> 6;

  int local[8];
  int s = 0;
#pragma unroll
  for (int q = 0; q < 8; ++q) {
    local[q] = ghist[tid * 8 + q];
    s += local[q];
  }

  int incl = s;  // wave-inclusive scan of per-thread sums
#pragma unroll
  for (int off = 1; off < 64; off <<= 1) {
    const int v = __shfl_up(incl, off);
    if (lane >= off) incl += v;
  }
  if (lane == 63) wsum[wid] = incl;
  __syncthreads();

  if (tid == 0) {
    int acc = 0;
#pragma unroll
    for (int w = 0; w < 16; ++w) { wexc[w] = acc; acc += wsum[w]; }
  }
  __syncthreads();

  int run = wexc[wid] + (incl - s);  // exclusive prefix of my 8-bin chunk
  int acc = 0;
#pragma unroll
  for (int q = 0; q < 8; ++q) {
    run += local[q];
    acc += (run < 0) ? -run : run;
  }

#pragma unroll
  for (int off = 32; off > 0; off >>= 1) acc += __shfl_down(acc, off);
  if (lane == 0) wabs[wid] = acc;
  __syncthreads();

  if (tid == 0) {
    int total = 0;
#pragma unroll
    for (int w = 0; w < 16; ++w) total += wabs[w];
    // result = total / (N-1) / N
    out[0] = (float)((double)total / ((double)(N - 1) * (double)N));
  }
}

extern "C" void kernel_launch(void* const* d_in, const int* in_sizes, int n_in,
                              void* d_out, int out_size, void* d_ws, size_t ws_size,
                              hipStream_t stream) {
  const float* X = (const float*)d_in[0];
  const float* Xh = (const float*)d_in[1];
  float* out = (float*)d_out;
  int* counts = (int*)d_ws;        // 2N ints
  int* ghist = counts + 2 * N;     // N ints, contiguous

  hipMemsetAsync(counts, 0, 3 * N * sizeof(int), stream);

  dim3 grid(NIT, JCH, 2);
  dom_count_kernel<<<grid, BLK, 0, stream>>>(X, Xh, counts);
  hist_partial_kernel<<<HB, 1024, 0, stream>>>(counts, ghist);
  finalize_kernel<<<1, 1024, 0, stream>>>(ghist, out);
}